// Round 4
// baseline (6495.137 us; speedup 1.0000x reference)
//
#include <hip/hip_runtime.h>
#include <cstdint>

typedef unsigned long long u64;

static constexpr int BB = 2;
static constexpr int NN = 16384;
static constexpr int SS = 4096;

// one step of a u64 max-combine via DPP (CTRL is a DPP control immediate)
template <int CTRL>
__device__ __forceinline__ u64 dpp_max_step(u64 k) {
  int lo = (int)(unsigned)(k & 0xffffffffull);
  int hi = (int)(unsigned)(k >> 32);
  int slo = __builtin_amdgcn_update_dpp(0, lo, CTRL, 0xF, 0xF, true);
  int shi = __builtin_amdgcn_update_dpp(0, hi, CTRL, 0xF, 0xF, true);
  u64 o = ((u64)(unsigned)shi << 32) | (u64)(unsigned)slo;
  return (o > k) ? o : k;
}

// ---------------------------------------------------------------------------
// FPS: one block per batch, 1024 threads, 16 consecutive points/thread in
// registers. R1-R3 lesson: without an explicit occupancy declaration the
// compiler capped VGPRs at 64 (targeting 8 waves/SIMD) and rematerialized the
// coordinate loads INSIDE the 4095-iteration loop (VGPR_Count 44-48,
// FETCH_SIZE ~200 MB = 48 KB/iter re-streamed). __launch_bounds__(1024, 4)
// raises the budget to 128 VGPRs (4 waves/EU is all a 2-block grid can use),
// and empty-asm pins make remat-by-reload impossible.
// Bit-exact distance math (separate mul/add, no FMA) to match numpy; argmax
// tie-break = lowest original index via packed key (dist_bits<<32)|~idx.
// ---------------------------------------------------------------------------
__global__ __launch_bounds__(1024, 4) void fps_kernel(
    const float* __restrict__ xyz, float* __restrict__ new_xyz)
{
  const int b = blockIdx.x;
  const float* X = xyz + (size_t)b * NN * 3;
  float* NX = new_xyz + (size_t)b * SS * 3;
  const int t = threadIdx.x;
  const int lane = t & 63;
  const int wid = t >> 6;
  const int base = t * 16;

  // 16 consecutive points = 192 B = 12 float4 loads, unpacked to named scalars
  const float4* P4 = (const float4*)(X + (size_t)t * 48);
  float4 g0 = P4[0], g1 = P4[1], g2 = P4[2], g3 = P4[3], g4 = P4[4], g5 = P4[5],
         g6 = P4[6], g7 = P4[7], g8 = P4[8], g9 = P4[9], g10 = P4[10], g11 = P4[11];
  float px0 = g0.x,  py0 = g0.y,  pz0 = g0.z;
  float px1 = g0.w,  py1 = g1.x,  pz1 = g1.y;
  float px2 = g1.z,  py2 = g1.w,  pz2 = g2.x;
  float px3 = g2.y,  py3 = g2.z,  pz3 = g2.w;
  float px4 = g3.x,  py4 = g3.y,  pz4 = g3.z;
  float px5 = g3.w,  py5 = g4.x,  pz5 = g4.y;
  float px6 = g4.z,  py6 = g4.w,  pz6 = g5.x;
  float px7 = g5.y,  py7 = g5.z,  pz7 = g5.w;
  float px8 = g6.x,  py8 = g6.y,  pz8 = g6.z;
  float px9 = g6.w,  py9 = g7.x,  pz9 = g7.y;
  float px10 = g7.z, py10 = g7.w, pz10 = g8.x;
  float px11 = g8.y, py11 = g8.z, pz11 = g8.w;
  float px12 = g9.x, py12 = g9.y, pz12 = g9.z;
  float px13 = g9.w, py13 = g10.x, pz13 = g10.y;
  float px14 = g10.z, py14 = g10.w, pz14 = g11.x;
  float px15 = g11.y, py15 = g11.z, pz15 = g11.w;

  // pin the 48 coord scalars into VGPRs: asm "writes" them, so the register
  // allocator can neither rematerialize the loads nor fold them away
  asm volatile("" : "+v"(px0), "+v"(py0), "+v"(pz0), "+v"(px1), "+v"(py1),
                    "+v"(pz1), "+v"(px2), "+v"(py2), "+v"(pz2), "+v"(px3),
                    "+v"(py3), "+v"(pz3), "+v"(px4), "+v"(py4), "+v"(pz4),
                    "+v"(px5));
  asm volatile("" : "+v"(py5), "+v"(pz5), "+v"(px6), "+v"(py6), "+v"(pz6),
                    "+v"(px7), "+v"(py7), "+v"(pz7), "+v"(px8), "+v"(py8),
                    "+v"(pz8), "+v"(px9), "+v"(py9), "+v"(pz9), "+v"(px10),
                    "+v"(py10));
  asm volatile("" : "+v"(pz10), "+v"(px11), "+v"(py11), "+v"(pz11), "+v"(px12),
                    "+v"(py12), "+v"(pz12), "+v"(px13), "+v"(py13), "+v"(pz13),
                    "+v"(px14), "+v"(py14), "+v"(pz14), "+v"(px15), "+v"(py15),
                    "+v"(pz15));

  float d0 = 1e10f, d1 = 1e10f, d2 = 1e10f, d3 = 1e10f,
        d4 = 1e10f, d5 = 1e10f, d6 = 1e10f, d7 = 1e10f,
        d8 = 1e10f, d9 = 1e10f, d10 = 1e10f, d11 = 1e10f,
        d12 = 1e10f, d13 = 1e10f, d14 = 1e10f, d15 = 1e10f;

  __shared__ u64 s_part[2][16];

  int sel = 0;  // selection of previous iteration (iteration 0 selects point 0)
  for (int it = 1; it < SS; ++it) {
    // winner coords: scalar (wave-uniform) load, L2-resident
    const float sx = X[sel * 3 + 0];
    const float sy = X[sel * 3 + 1];
    const float sz = X[sel * 3 + 2];
    // deferred store of previous selection; drains under the update phase
    if (t == 0) {
      NX[(it - 1) * 3 + 0] = sx;
      NX[(it - 1) * 3 + 1] = sy;
      NX[(it - 1) * 3 + 2] = sz;
    }

    float bval = -1.f;
    int bidx = 0;
#define UPD(dd, ax, ay, az, ii)                                              \
    {                                                                        \
      float dx = __fsub_rn(ax, sx);                                          \
      float dy = __fsub_rn(ay, sy);                                          \
      float dz = __fsub_rn(az, sz);                                          \
      float dsq = __fadd_rn(__fadd_rn(__fmul_rn(dx, dx), __fmul_rn(dy, dy)), \
                            __fmul_rn(dz, dz));                              \
      dd = fminf(dd, dsq);                                                   \
      if (dd > bval) { bval = dd; bidx = base + ii; }                        \
    }
    UPD(d0,  px0,  py0,  pz0,  0)
    UPD(d1,  px1,  py1,  pz1,  1)
    UPD(d2,  px2,  py2,  pz2,  2)
    UPD(d3,  px3,  py3,  pz3,  3)
    UPD(d4,  px4,  py4,  pz4,  4)
    UPD(d5,  px5,  py5,  pz5,  5)
    UPD(d6,  px6,  py6,  pz6,  6)
    UPD(d7,  px7,  py7,  pz7,  7)
    UPD(d8,  px8,  py8,  pz8,  8)
    UPD(d9,  px9,  py9,  pz9,  9)
    UPD(d10, px10, py10, pz10, 10)
    UPD(d11, px11, py11, pz11, 11)
    UPD(d12, px12, py12, pz12, 12)
    UPD(d13, px13, py13, pz13, 13)
    UPD(d14, px14, py14, pz14, 14)
    UPD(d15, px15, py15, pz15, 15)
#undef UPD

    // packed key: max dist wins; on equal dist, ~idx max -> lowest index wins
    u64 k = ((u64)__float_as_uint(bval) << 32) | (u64)(unsigned)(~bidx);
    // wave argmax: prefix combine, full wave max lands in lane 63
    k = dpp_max_step<0x111>(k);  // row_shr:1
    k = dpp_max_step<0x112>(k);  // row_shr:2
    k = dpp_max_step<0x114>(k);  // row_shr:4
    k = dpp_max_step<0x118>(k);  // row_shr:8
    k = dpp_max_step<0x142>(k);  // row_bcast:15
    k = dpp_max_step<0x143>(k);  // row_bcast:31

    const int pb = it & 1;
    if (lane == 63) s_part[pb][wid] = k;
    __syncthreads();
    // every wave redundantly reduces the 16 partials; ror reduce -> all lanes
    u64 kk = s_part[pb][lane & 15];
    kk = dpp_max_step<0x128>(kk);  // row_ror:8
    kk = dpp_max_step<0x124>(kk);  // row_ror:4
    kk = dpp_max_step<0x122>(kk);  // row_ror:2
    kk = dpp_max_step<0x121>(kk);  // row_ror:1
    sel = (int)(~(unsigned)(kk & 0xffffffffull));
    sel = __builtin_amdgcn_readfirstlane(sel);
  }
  if (t == 0) {
    NX[(SS - 1) * 3 + 0] = X[sel * 3 + 0];
    NX[(SS - 1) * 3 + 1] = X[sel * 3 + 1];
    NX[(SS - 1) * 3 + 2] = X[sel * 3 + 2];
  }
}

// ---------------------------------------------------------------------------
// Ball query: one 64-lane wave per query point. Emits the first NS in-radius
// point indices in ascending order (matches reference top_k(-keys) trick),
// pads with the first hit.
// ---------------------------------------------------------------------------
template <int NS>
__global__ __launch_bounds__(256) void ballq_kernel(
    const float* __restrict__ xyz, const float* __restrict__ new_xyz,
    int* __restrict__ out, float r2)
{
  const int q = blockIdx.x * 4 + (threadIdx.x >> 6);
  const int lane = threadIdx.x & 63;
  const int b = q >> 12;  // q / SS
  const float* X = xyz + (size_t)b * NN * 3;
  const float cx = new_xyz[q * 3 + 0];
  const float cy = new_xyz[q * 3 + 1];
  const float cz = new_xyz[q * 3 + 2];
  int* o = out + (size_t)q * NS;
  int base = 0;
  int firstIdx = 0x7fffffff;
  for (int c0 = 0; c0 < NN; c0 += 64) {
    const int p = c0 + lane;
    float dx = __fsub_rn(cx, X[p * 3 + 0]);
    float dy = __fsub_rn(cy, X[p * 3 + 1]);
    float dz = __fsub_rn(cz, X[p * 3 + 2]);
    float d2 = __fadd_rn(__fadd_rn(__fmul_rn(dx, dx), __fmul_rn(dy, dy)),
                         __fmul_rn(dz, dz));
    const bool inb = d2 < r2;
    const unsigned long long m = __ballot(inb);
    if (inb) {
      int rank = base + (int)__popcll(m & ((1ull << lane) - 1ull));
      if (rank < NS) {
        o[rank] = p;
        if (rank == 0) firstIdx = p;
      }
    }
    base += (int)__popcll(m);
    if (base >= NS) break;
  }
#pragma unroll
  for (int off = 32; off >= 1; off >>= 1)
    firstIdx = min(firstIdx, __shfl_xor(firstIdx, off));
  for (int r = base + lane; r < NS; r += 64) o[r] = firstIdx;
}

// ---------------------------------------------------------------------------
// Grouping + 3-layer MLP + max over samples. One thread per (query, sample).
// Weights read with wave-uniform indices -> scalar loads.
// ---------------------------------------------------------------------------
template <int NS, int C1, int C2, int C3>
__global__ __launch_bounds__(256) void group_mlp_kernel(
    const float* __restrict__ xyz, const float* __restrict__ feat,
    const float* __restrict__ new_xyz, const int* __restrict__ idx,
    const float* __restrict__ w0, const float* __restrict__ b0,
    const float* __restrict__ w1, const float* __restrict__ b1,
    const float* __restrict__ w2, const float* __restrict__ b2,
    float* __restrict__ pf, int chOff)
{
  constexpr int QPB = 256 / NS;
  const int q = blockIdx.x * QPB + (int)(threadIdx.x / NS);
  const int k = (int)(threadIdx.x % NS);
  const int b = q >> 12;
  const int s = q & (SS - 1);
  const float* X = xyz + (size_t)b * NN * 3;
  const float* F = feat + (size_t)b * 6 * NN;
  const int p = idx[(size_t)q * NS + k];

  float in[9];
  in[0] = X[p * 3 + 0] - new_xyz[q * 3 + 0];
  in[1] = X[p * 3 + 1] - new_xyz[q * 3 + 1];
  in[2] = X[p * 3 + 2] - new_xyz[q * 3 + 2];
#pragma unroll
  for (int c = 0; c < 6; ++c) in[3 + c] = F[c * NN + p];

  float h1[C1];
#pragma unroll
  for (int oc = 0; oc < C1; ++oc) {
    float a = b0[oc];
#pragma unroll
    for (int c = 0; c < 9; ++c) a = fmaf(w0[oc * 9 + c], in[c], a);
    h1[oc] = fmaxf(a, 0.f);
  }
  float h2[C2];
#pragma unroll
  for (int oc = 0; oc < C2; ++oc) {
    float a = b1[oc];
#pragma unroll
    for (int c = 0; c < C1; ++c) a = fmaf(w1[oc * C1 + c], h1[c], a);
    h2[oc] = fmaxf(a, 0.f);
  }
  // third layer: compute one output channel at a time, reduce immediately
#pragma unroll
  for (int oc = 0; oc < C3; ++oc) {
    float a = b2[oc];
#pragma unroll
    for (int c = 0; c < C2; ++c) a = fmaf(w2[oc * C2 + c], h2[c], a);
    float v = fmaxf(a, 0.f);
#pragma unroll
    for (int off = NS / 2; off >= 1; off >>= 1)
      v = fmaxf(v, __shfl_xor(v, off));
    if (k == 0) pf[(((size_t)b * 96) + chOff + oc) * SS + s] = v;
  }
}

// ---------------------------------------------------------------------------
// Image branch + attention + fusion, 32-column LDS tiles.
// ---------------------------------------------------------------------------
__global__ __launch_bounds__(256) void img_fuse_kernel(
    const float* __restrict__ imgf, const float* __restrict__ pf,
    const float* __restrict__ w_img, const float* __restrict__ b_img,
    const float* __restrict__ w_fc2, const float* __restrict__ b_fc2,
    const float* __restrict__ w_fc3, const float* __restrict__ b_fc3,
    const float* __restrict__ w_pc, const float* __restrict__ b_pc,
    const float* __restrict__ w_fuse, const float* __restrict__ b_fuse,
    float* __restrict__ out)
{
  constexpr int TS = 32;
  __shared__ float x_lds[64][TS];
  __shared__ float img_lds[96][TS];
  __shared__ float ri_lds[24][TS];
  __shared__ float att_lds[TS];
  __shared__ float imgn_lds[96][TS];
  __shared__ float pf_lds[96][TS];

  const int blk = blockIdx.x;            // B * (SS/TS) = 256 blocks
  const int b = blk / (SS / TS);
  const int s0 = (blk % (SS / TS)) * TS;
  const int tid = threadIdx.x;

  for (int i = tid; i < 64 * TS; i += 256) {
    int c = i / TS, s = i % TS;
    x_lds[c][s] = imgf[((size_t)b * 64 + c) * SS + s0 + s];
  }
  for (int i = tid; i < 96 * TS; i += 256) {
    int c = i / TS, s = i % TS;
    pf_lds[c][s] = pf[((size_t)b * 96 + c) * SS + s0 + s];
  }
  __syncthreads();

  // img = relu(w_img @ x + b)
  for (int i = tid; i < 96 * TS; i += 256) {
    int oc = i / TS, s = i % TS;
    float a = b_img[oc];
#pragma unroll
    for (int c = 0; c < 64; ++c) a = fmaf(w_img[oc * 64 + c], x_lds[c][s], a);
    img_lds[oc][s] = fmaxf(a, 0.f);
  }
  __syncthreads();

  // ri = tanh(img^T @ w_fc2^T + b)
  for (int i = tid; i < 24 * TS; i += 256) {
    int r = i / TS, s = i % TS;
    float a = b_fc2[r];
#pragma unroll
    for (int c = 0; c < 96; ++c) a = fmaf(w_fc2[r * 96 + c], img_lds[c][s], a);
    ri_lds[r][s] = tanhf(a);
  }
  __syncthreads();

  if (tid < TS) {
    float a = b_fc3[0];
#pragma unroll
    for (int r = 0; r < 24; ++r) a = fmaf(w_fc3[r], ri_lds[r][tid], a);
    att_lds[tid] = 1.f / (1.f + expf(-a));
  }
  __syncthreads();

  // img_r = img + img*att (in place)
  for (int i = tid; i < 96 * TS; i += 256) {
    int c = i / TS, s = i % TS;
    float v = img_lds[c][s];
    img_lds[c][s] = fmaf(v, att_lds[s], v);
  }
  __syncthreads();

  // img_new = relu(w_pc @ img_r + b)
  for (int i = tid; i < 96 * TS; i += 256) {
    int oc = i / TS, s = i % TS;
    float a = b_pc[oc];
#pragma unroll
    for (int c = 0; c < 96; ++c) a = fmaf(w_pc[oc * 96 + c], img_lds[c][s], a);
    imgn_lds[oc][s] = fmaxf(a, 0.f);
  }
  __syncthreads();

  // out = relu(w_fuse @ [pf ; img_new] + b)
  for (int i = tid; i < 128 * TS; i += 256) {
    int oc = i / TS, s = i % TS;
    float a = b_fuse[oc];
#pragma unroll
    for (int c = 0; c < 96; ++c) a = fmaf(w_fuse[oc * 192 + c], pf_lds[c][s], a);
#pragma unroll
    for (int c = 0; c < 96; ++c) a = fmaf(w_fuse[oc * 192 + 96 + c], imgn_lds[c][s], a);
    out[((size_t)b * 128 + oc) * SS + s0 + s] = fmaxf(a, 0.f);
  }
}

// ---------------------------------------------------------------------------
extern "C" void kernel_launch(void* const* d_in, const int* in_sizes, int n_in,
                              void* d_out, int out_size, void* d_ws, size_t ws_size,
                              hipStream_t stream)
{
  const float* xyz    = (const float*)d_in[0];
  const float* feat   = (const float*)d_in[1];
  const float* imgf   = (const float*)d_in[2];
  const float* w0_0   = (const float*)d_in[3];
  const float* b0_0   = (const float*)d_in[4];
  const float* w0_1   = (const float*)d_in[5];
  const float* b0_1   = (const float*)d_in[6];
  const float* w0_2   = (const float*)d_in[7];
  const float* b0_2   = (const float*)d_in[8];
  const float* w1_0   = (const float*)d_in[9];
  const float* b1_0   = (const float*)d_in[10];
  const float* w1_1   = (const float*)d_in[11];
  const float* b1_1   = (const float*)d_in[12];
  const float* w1_2   = (const float*)d_in[13];
  const float* b1_2   = (const float*)d_in[14];
  const float* w_img  = (const float*)d_in[15];
  const float* b_img  = (const float*)d_in[16];
  const float* w_fc2  = (const float*)d_in[17];
  const float* b_fc2  = (const float*)d_in[18];
  const float* w_fc3  = (const float*)d_in[19];
  const float* b_fc3  = (const float*)d_in[20];
  const float* w_pc   = (const float*)d_in[21];
  const float* b_pc   = (const float*)d_in[22];
  const float* w_fuse = (const float*)d_in[23];
  const float* b_fuse = (const float*)d_in[24];
  float* out = (float*)d_out;

  float* nxyz = (float*)d_ws;                          // B*S*3 f32
  int*   idx0 = (int*)(nxyz + (size_t)BB * SS * 3);    // B*S*16 i32
  int*   idx1 = idx0 + (size_t)BB * SS * 16;           // B*S*32 i32
  float* pf   = (float*)(idx1 + (size_t)BB * SS * 32); // B*96*S f32

  fps_kernel<<<BB, 1024, 0, stream>>>(xyz, nxyz);
  ballq_kernel<16><<<BB * SS / 4, 256, 0, stream>>>(xyz, nxyz, idx0, 0.25f);
  ballq_kernel<32><<<BB * SS / 4, 256, 0, stream>>>(xyz, nxyz, idx1, 1.0f);
  group_mlp_kernel<16, 16, 16, 32><<<BB * SS / 16, 256, 0, stream>>>(
      xyz, feat, nxyz, idx0, w0_0, b0_0, w0_1, b0_1, w0_2, b0_2, pf, 0);
  group_mlp_kernel<32, 32, 32, 64><<<BB * SS / 8, 256, 0, stream>>>(
      xyz, feat, nxyz, idx1, w1_0, b1_0, w1_1, b1_1, w1_2, b1_2, pf, 32);
  img_fuse_kernel<<<BB * SS / 32, 256, 0, stream>>>(
      imgf, pf, w_img, b_img, w_fc2, b_fc2, w_fc3, b_fc3, w_pc, b_pc,
      w_fuse, b_fuse, out);
}

// Round 5
// 4346.844 us; speedup vs baseline: 1.4942x; 1.4942x over previous
//
#include <hip/hip_runtime.h>
#include <cstdint>

typedef unsigned long long u64;

static constexpr int BB = 2;
static constexpr int NN = 16384;
static constexpr int SS = 4096;

// one step of a u64 max-combine via DPP (CTRL is a DPP control immediate)
template <int CTRL>
__device__ __forceinline__ u64 dpp_max_step(u64 k) {
  int lo = (int)(unsigned)(k & 0xffffffffull);
  int hi = (int)(unsigned)(k >> 32);
  int slo = __builtin_amdgcn_update_dpp(0, lo, CTRL, 0xF, 0xF, true);
  int shi = __builtin_amdgcn_update_dpp(0, hi, CTRL, 0xF, 0xF, true);
  u64 o = ((u64)(unsigned)shi << 32) | (u64)(unsigned)slo;
  return (o > k) ? o : k;
}

// spread 4 bits: bit k -> bit 3k (for 12-bit Morton)
__device__ __forceinline__ unsigned spread4(unsigned v) {
  return (v & 1u) | ((v & 2u) << 2) | ((v & 4u) << 4) | ((v & 8u) << 6);
}

__device__ __forceinline__ unsigned cell_of(float x, float y, float z) {
  int cx = (int)floorf((x + 4.f) * 2.f);
  int cy = (int)floorf((y + 4.f) * 2.f);
  int cz = (int)floorf((z + 4.f) * 2.f);
  cx = min(max(cx, 0), 15); cy = min(max(cy, 0), 15); cz = min(max(cz, 0), 15);
  return spread4((unsigned)cx) | (spread4((unsigned)cy) << 1) |
         (spread4((unsigned)cz) << 2);
}

// ---------------------------------------------------------------------------
// Counting sort by 12-bit Morton cell. One block per batch. Gives each FPS
// wave (1024 consecutive sorted points) a spatially compact region so the
// wave-level bbox pruning in fps_kernel has high skip rates.
// NOTE: scatter order within a cell is atomic-order nondeterministic, but the
// FPS output is invariant to it (argmax keys carry original indices; skipped
// updates are provably no-ops) -> output stays deterministic.
// ---------------------------------------------------------------------------
__global__ __launch_bounds__(1024) void sort_kernel(
    const float* __restrict__ xyz,
    float* __restrict__ sx, float* __restrict__ sy,
    float* __restrict__ sz, int* __restrict__ sidx)
{
  const int b = blockIdx.x;
  const float* X = xyz + (size_t)b * NN * 3;
  float* SX = sx + (size_t)b * NN;
  float* SY = sy + (size_t)b * NN;
  float* SZ = sz + (size_t)b * NN;
  int*   SI = sidx + (size_t)b * NN;
  const int t = threadIdx.x;
  const int lane = t & 63, wid = t >> 6;

  __shared__ unsigned h[4096];
  __shared__ unsigned wtot[16];
  for (int j = t; j < 4096; j += 1024) h[j] = 0;
  __syncthreads();

  // count
  for (int i = 0; i < 16; ++i) {
    int p = i * 1024 + t;
    float x = X[p * 3 + 0], y = X[p * 3 + 1], z = X[p * 3 + 2];
    atomicAdd(&h[cell_of(x, y, z)], 1u);
  }
  __syncthreads();

  // exclusive scan of h[4096]: 4 entries/thread -> wave scan -> block combine
  unsigned a0 = h[4 * t], a1 = h[4 * t + 1], a2 = h[4 * t + 2], a3 = h[4 * t + 3];
  unsigned s4 = a0 + a1 + a2 + a3;
  unsigned incl = s4;
  for (int off = 1; off < 64; off <<= 1) {
    unsigned v = (unsigned)__shfl_up((int)incl, off);
    if (lane >= off) incl += v;
  }
  if (lane == 63) wtot[wid] = incl;
  __syncthreads();
  if (t == 0) {
    unsigned run = 0;
    for (int j = 0; j < 16; ++j) { unsigned tm = wtot[j]; wtot[j] = run; run += tm; }
  }
  __syncthreads();
  unsigned ex = wtot[wid] + (incl - s4);
  h[4 * t] = ex; h[4 * t + 1] = ex + a0;
  h[4 * t + 2] = ex + a0 + a1; h[4 * t + 3] = ex + a0 + a1 + a2;
  __syncthreads();

  // scatter
  for (int i = 0; i < 16; ++i) {
    int p = i * 1024 + t;
    float x = X[p * 3 + 0], y = X[p * 3 + 1], z = X[p * 3 + 2];
    unsigned pos = atomicAdd(&h[cell_of(x, y, z)], 1u);
    SX[pos] = x; SY[pos] = y; SZ[pos] = z; SI[pos] = p;
  }
}

// ---------------------------------------------------------------------------
// FPS with exact wave-level bbox pruning. One block per batch, 1024 threads,
// 16 sorted points/thread in named registers. Per iteration a wave either
// (a) proves min-dist(s, wave-bbox)^2 * (1-2^-16) >= its current max dist ->
//     every suppressed fmin update is a no-op even under the reference's fp
//     rounding -> skip the 16-point update entirely (whole-wave branch), or
// (b) runs the bit-exact update (separate mul/add, no FMA) and re-reduces its
//     argmax key. Keys are (dist_bits<<32)|~orig_idx -> numpy-exact argmax
//     with first-original-index tie-break, invariant to the sort permutation.
// ---------------------------------------------------------------------------
__global__ __attribute__((amdgpu_waves_per_eu(4, 4))) __launch_bounds__(1024)
void fps_kernel(const float* __restrict__ xyz,
                const float* __restrict__ sx, const float* __restrict__ sy,
                const float* __restrict__ sz, const int* __restrict__ sidx,
                float* __restrict__ new_xyz)
{
  const int b = blockIdx.x;
  const float* X = xyz + (size_t)b * NN * 3;
  float* NX = new_xyz + (size_t)b * SS * 3;
  const float* SX = sx + (size_t)b * NN;
  const float* SY = sy + (size_t)b * NN;
  const float* SZ = sz + (size_t)b * NN;
  const int*   SI = sidx + (size_t)b * NN;
  const int t = threadIdx.x;
  const int lane = t & 63, wid = t >> 6;

  const float4* AX = (const float4*)(SX + (size_t)t * 16);
  const float4* AY = (const float4*)(SY + (size_t)t * 16);
  const float4* AZ = (const float4*)(SZ + (size_t)t * 16);
  const int4*   AI = (const int4*)(SI + (size_t)t * 16);
  float4 x0 = AX[0], x1 = AX[1], x2 = AX[2], x3 = AX[3];
  float4 y0 = AY[0], y1 = AY[1], y2 = AY[2], y3 = AY[3];
  float4 z0 = AZ[0], z1 = AZ[1], z2 = AZ[2], z3 = AZ[3];
  int4   i0 = AI[0], i1 = AI[1], i2 = AI[2], i3 = AI[3];

  float px0 = x0.x, px1 = x0.y, px2 = x0.z, px3 = x0.w,
        px4 = x1.x, px5 = x1.y, px6 = x1.z, px7 = x1.w,
        px8 = x2.x, px9 = x2.y, px10 = x2.z, px11 = x2.w,
        px12 = x3.x, px13 = x3.y, px14 = x3.z, px15 = x3.w;
  float py0 = y0.x, py1 = y0.y, py2 = y0.z, py3 = y0.w,
        py4 = y1.x, py5 = y1.y, py6 = y1.z, py7 = y1.w,
        py8 = y2.x, py9 = y2.y, py10 = y2.z, py11 = y2.w,
        py12 = y3.x, py13 = y3.y, py14 = y3.z, py15 = y3.w;
  float pz0 = z0.x, pz1 = z0.y, pz2 = z0.z, pz3 = z0.w,
        pz4 = z1.x, pz5 = z1.y, pz6 = z1.z, pz7 = z1.w,
        pz8 = z2.x, pz9 = z2.y, pz10 = z2.z, pz11 = z2.w,
        pz12 = z3.x, pz13 = z3.y, pz14 = z3.z, pz15 = z3.w;
  // ~orig_idx (low half of the argmax key; max => lowest original index wins)
  unsigned ni0 = ~(unsigned)i0.x, ni1 = ~(unsigned)i0.y, ni2 = ~(unsigned)i0.z,
           ni3 = ~(unsigned)i0.w, ni4 = ~(unsigned)i1.x, ni5 = ~(unsigned)i1.y,
           ni6 = ~(unsigned)i1.z, ni7 = ~(unsigned)i1.w, ni8 = ~(unsigned)i2.x,
           ni9 = ~(unsigned)i2.y, ni10 = ~(unsigned)i2.z, ni11 = ~(unsigned)i2.w,
           ni12 = ~(unsigned)i3.x, ni13 = ~(unsigned)i3.y, ni14 = ~(unsigned)i3.z,
           ni15 = ~(unsigned)i3.w;

  float d0 = 1e10f, d1 = 1e10f, d2 = 1e10f, d3 = 1e10f,
        d4 = 1e10f, d5 = 1e10f, d6 = 1e10f, d7 = 1e10f,
        d8 = 1e10f, d9 = 1e10f, d10 = 1e10f, d11 = 1e10f,
        d12 = 1e10f, d13 = 1e10f, d14 = 1e10f, d15 = 1e10f;

  // per-lane bbox over 16 points, then wave-wide via xor-shuffle (all lanes)
  float bnx = fminf(fminf(fminf(px0, px1), fminf(px2, px3)),
                    fminf(fminf(px4, px5), fminf(px6, px7)));
  bnx = fminf(bnx, fminf(fminf(fminf(px8, px9), fminf(px10, px11)),
                         fminf(fminf(px12, px13), fminf(px14, px15))));
  float bxx = fmaxf(fmaxf(fmaxf(px0, px1), fmaxf(px2, px3)),
                    fmaxf(fmaxf(px4, px5), fmaxf(px6, px7)));
  bxx = fmaxf(bxx, fmaxf(fmaxf(fmaxf(px8, px9), fmaxf(px10, px11)),
                         fmaxf(fmaxf(px12, px13), fmaxf(px14, px15))));
  float bny = fminf(fminf(fminf(py0, py1), fminf(py2, py3)),
                    fminf(fminf(py4, py5), fminf(py6, py7)));
  bny = fminf(bny, fminf(fminf(fminf(py8, py9), fminf(py10, py11)),
                         fminf(fminf(py12, py13), fminf(py14, py15))));
  float bxy = fmaxf(fmaxf(fmaxf(py0, py1), fmaxf(py2, py3)),
                    fmaxf(fmaxf(py4, py5), fmaxf(py6, py7)));
  bxy = fmaxf(bxy, fmaxf(fmaxf(fmaxf(py8, py9), fmaxf(py10, py11)),
                         fmaxf(fmaxf(py12, py13), fmaxf(py14, py15))));
  float bnz = fminf(fminf(fminf(pz0, pz1), fminf(pz2, pz3)),
                    fminf(fminf(pz4, pz5), fminf(pz6, pz7)));
  bnz = fminf(bnz, fminf(fminf(fminf(pz8, pz9), fminf(pz10, pz11)),
                         fminf(fminf(pz12, pz13), fminf(pz14, pz15))));
  float bxz = fmaxf(fmaxf(fmaxf(pz0, pz1), fmaxf(pz2, pz3)),
                    fmaxf(fmaxf(pz4, pz5), fmaxf(pz6, pz7)));
  bxz = fmaxf(bxz, fmaxf(fmaxf(fmaxf(pz8, pz9), fmaxf(pz10, pz11)),
                         fmaxf(fmaxf(pz12, pz13), fmaxf(pz14, pz15))));
#pragma unroll
  for (int off = 1; off < 64; off <<= 1) {
    bnx = fminf(bnx, __shfl_xor(bnx, off));
    bxx = fmaxf(bxx, __shfl_xor(bxx, off));
    bny = fminf(bny, __shfl_xor(bny, off));
    bxy = fmaxf(bxy, __shfl_xor(bxy, off));
    bnz = fminf(bnz, __shfl_xor(bnz, off));
    bxz = fmaxf(bxz, __shfl_xor(bxz, off));
  }

  __shared__ u64 s_part[2][16];
  u64 kc = 0;            // cached wave argmax key
  float wmaxf = 1e10f;   // cached wave max dist (hi bits of kc as float)
  int sel = 0;

  for (int it = 1; it < SS; ++it) {
    const float qx = X[sel * 3 + 0];
    const float qy = X[sel * 3 + 1];
    const float qz = X[sel * 3 + 2];
    if (t == 0) {
      NX[(it - 1) * 3 + 0] = qx;
      NX[(it - 1) * 3 + 1] = qy;
      NX[(it - 1) * 3 + 2] = qz;
    }

    // conservative lower bound of dist^2(q, wave bbox); margin (1-2^-16)
    // covers our rounding + the reference's (~2^-19 total) -> skips are
    // provably no-op fmin updates.
    float tx = fmaxf(fmaxf(__fsub_rn(bnx, qx), __fsub_rn(qx, bxx)), 0.f);
    float ty = fmaxf(fmaxf(__fsub_rn(bny, qy), __fsub_rn(qy, bxy)), 0.f);
    float tz = fmaxf(fmaxf(__fsub_rn(bnz, qz), __fsub_rn(qz, bxz)), 0.f);
    float lb2 = fmaf(tx, tx, fmaf(ty, ty, tz * tz));

    if (!(lb2 * 0.99998474f >= wmaxf)) {   // wave-uniform branch
      u64 kbest = 0;
#define UPD(dd, ax, ay, az, nn)                                              \
      {                                                                      \
        float dx = __fsub_rn(ax, qx);                                        \
        float dy = __fsub_rn(ay, qy);                                        \
        float dz = __fsub_rn(az, qz);                                        \
        float dsq = __fadd_rn(__fadd_rn(__fmul_rn(dx, dx), __fmul_rn(dy, dy)),\
                              __fmul_rn(dz, dz));                            \
        dd = fminf(dd, dsq);                                                 \
        u64 kp = ((u64)__float_as_uint(dd) << 32) | (u64)(nn);               \
        if (kp > kbest) kbest = kp;                                          \
      }
      UPD(d0,  px0,  py0,  pz0,  ni0)
      UPD(d1,  px1,  py1,  pz1,  ni1)
      UPD(d2,  px2,  py2,  pz2,  ni2)
      UPD(d3,  px3,  py3,  pz3,  ni3)
      UPD(d4,  px4,  py4,  pz4,  ni4)
      UPD(d5,  px5,  py5,  pz5,  ni5)
      UPD(d6,  px6,  py6,  pz6,  ni6)
      UPD(d7,  px7,  py7,  pz7,  ni7)
      UPD(d8,  px8,  py8,  pz8,  ni8)
      UPD(d9,  px9,  py9,  pz9,  ni9)
      UPD(d10, px10, py10, pz10, ni10)
      UPD(d11, px11, py11, pz11, ni11)
      UPD(d12, px12, py12, pz12, ni12)
      UPD(d13, px13, py13, pz13, ni13)
      UPD(d14, px14, py14, pz14, ni14)
      UPD(d15, px15, py15, pz15, ni15)
#undef UPD
      u64 k = kbest;
      k = dpp_max_step<0x111>(k);  // row_shr:1
      k = dpp_max_step<0x112>(k);  // row_shr:2
      k = dpp_max_step<0x114>(k);  // row_shr:4
      k = dpp_max_step<0x118>(k);  // row_shr:8
      k = dpp_max_step<0x142>(k);  // row_bcast:15
      k = dpp_max_step<0x143>(k);  // row_bcast:31
      // broadcast lane 63's full-wave key to all lanes; cache it
      unsigned klo = (unsigned)__shfl((int)(unsigned)(k & 0xffffffffull), 63);
      unsigned khi = (unsigned)__shfl((int)(unsigned)(k >> 32), 63);
      kc = ((u64)khi << 32) | (u64)klo;
      wmaxf = __uint_as_float(khi);
    }

    const int pb = it & 1;
    if (lane == 63) s_part[pb][wid] = kc;
    __syncthreads();
    u64 kk = s_part[pb][lane & 15];
    kk = dpp_max_step<0x128>(kk);  // row_ror:8
    kk = dpp_max_step<0x124>(kk);  // row_ror:4
    kk = dpp_max_step<0x122>(kk);  // row_ror:2
    kk = dpp_max_step<0x121>(kk);  // row_ror:1
    sel = (int)(~(unsigned)(kk & 0xffffffffull));
    sel = __builtin_amdgcn_readfirstlane(sel);
  }
  if (t == 0) {
    NX[(SS - 1) * 3 + 0] = X[sel * 3 + 0];
    NX[(SS - 1) * 3 + 1] = X[sel * 3 + 1];
    NX[(SS - 1) * 3 + 2] = X[sel * 3 + 2];
  }
}

// ---------------------------------------------------------------------------
// Ball query: one 64-lane wave per query point. Emits the first NS in-radius
// point indices in ascending order (matches reference top_k(-keys) trick),
// pads with the first hit.
// ---------------------------------------------------------------------------
template <int NS>
__global__ __launch_bounds__(256) void ballq_kernel(
    const float* __restrict__ xyz, const float* __restrict__ new_xyz,
    int* __restrict__ out, float r2)
{
  const int q = blockIdx.x * 4 + (threadIdx.x >> 6);
  const int lane = threadIdx.x & 63;
  const int b = q >> 12;  // q / SS
  const float* X = xyz + (size_t)b * NN * 3;
  const float cx = new_xyz[q * 3 + 0];
  const float cy = new_xyz[q * 3 + 1];
  const float cz = new_xyz[q * 3 + 2];
  int* o = out + (size_t)q * NS;
  int base = 0;
  int firstIdx = 0x7fffffff;
  for (int c0 = 0; c0 < NN; c0 += 64) {
    const int p = c0 + lane;
    float dx = __fsub_rn(cx, X[p * 3 + 0]);
    float dy = __fsub_rn(cy, X[p * 3 + 1]);
    float dz = __fsub_rn(cz, X[p * 3 + 2]);
    float d2 = __fadd_rn(__fadd_rn(__fmul_rn(dx, dx), __fmul_rn(dy, dy)),
                         __fmul_rn(dz, dz));
    const bool inb = d2 < r2;
    const unsigned long long m = __ballot(inb);
    if (inb) {
      int rank = base + (int)__popcll(m & ((1ull << lane) - 1ull));
      if (rank < NS) {
        o[rank] = p;
        if (rank == 0) firstIdx = p;
      }
    }
    base += (int)__popcll(m);
    if (base >= NS) break;
  }
#pragma unroll
  for (int off = 32; off >= 1; off >>= 1)
    firstIdx = min(firstIdx, __shfl_xor(firstIdx, off));
  for (int r = base + lane; r < NS; r += 64) o[r] = firstIdx;
}

// ---------------------------------------------------------------------------
// Grouping + 3-layer MLP + max over samples. One thread per (query, sample).
// ---------------------------------------------------------------------------
template <int NS, int C1, int C2, int C3>
__global__ __launch_bounds__(256) void group_mlp_kernel(
    const float* __restrict__ xyz, const float* __restrict__ feat,
    const float* __restrict__ new_xyz, const int* __restrict__ idx,
    const float* __restrict__ w0, const float* __restrict__ b0,
    const float* __restrict__ w1, const float* __restrict__ b1,
    const float* __restrict__ w2, const float* __restrict__ b2,
    float* __restrict__ pf, int chOff)
{
  constexpr int QPB = 256 / NS;
  const int q = blockIdx.x * QPB + (int)(threadIdx.x / NS);
  const int k = (int)(threadIdx.x % NS);
  const int b = q >> 12;
  const int s = q & (SS - 1);
  const float* X = xyz + (size_t)b * NN * 3;
  const float* F = feat + (size_t)b * 6 * NN;
  const int p = idx[(size_t)q * NS + k];

  float in[9];
  in[0] = X[p * 3 + 0] - new_xyz[q * 3 + 0];
  in[1] = X[p * 3 + 1] - new_xyz[q * 3 + 1];
  in[2] = X[p * 3 + 2] - new_xyz[q * 3 + 2];
#pragma unroll
  for (int c = 0; c < 6; ++c) in[3 + c] = F[c * NN + p];

  float h1[C1];
#pragma unroll
  for (int oc = 0; oc < C1; ++oc) {
    float a = b0[oc];
#pragma unroll
    for (int c = 0; c < 9; ++c) a = fmaf(w0[oc * 9 + c], in[c], a);
    h1[oc] = fmaxf(a, 0.f);
  }
  float h2[C2];
#pragma unroll
  for (int oc = 0; oc < C2; ++oc) {
    float a = b1[oc];
#pragma unroll
    for (int c = 0; c < C1; ++c) a = fmaf(w1[oc * C1 + c], h1[c], a);
    h2[oc] = fmaxf(a, 0.f);
  }
#pragma unroll
  for (int oc = 0; oc < C3; ++oc) {
    float a = b2[oc];
#pragma unroll
    for (int c = 0; c < C2; ++c) a = fmaf(w2[oc * C2 + c], h2[c], a);
    float v = fmaxf(a, 0.f);
#pragma unroll
    for (int off = NS / 2; off >= 1; off >>= 1)
      v = fmaxf(v, __shfl_xor(v, off));
    if (k == 0) pf[(((size_t)b * 96) + chOff + oc) * SS + s] = v;
  }
}

// ---------------------------------------------------------------------------
// Image branch + attention + fusion, 32-column LDS tiles.
// ---------------------------------------------------------------------------
__global__ __launch_bounds__(256) void img_fuse_kernel(
    const float* __restrict__ imgf, const float* __restrict__ pf,
    const float* __restrict__ w_img, const float* __restrict__ b_img,
    const float* __restrict__ w_fc2, const float* __restrict__ b_fc2,
    const float* __restrict__ w_fc3, const float* __restrict__ b_fc3,
    const float* __restrict__ w_pc, const float* __restrict__ b_pc,
    const float* __restrict__ w_fuse, const float* __restrict__ b_fuse,
    float* __restrict__ out)
{
  constexpr int TS = 32;
  __shared__ float x_lds[64][TS];
  __shared__ float img_lds[96][TS];
  __shared__ float ri_lds[24][TS];
  __shared__ float att_lds[TS];
  __shared__ float imgn_lds[96][TS];
  __shared__ float pf_lds[96][TS];

  const int blk = blockIdx.x;            // B * (SS/TS) = 256 blocks
  const int b = blk / (SS / TS);
  const int s0 = (blk % (SS / TS)) * TS;
  const int tid = threadIdx.x;

  for (int i = tid; i < 64 * TS; i += 256) {
    int c = i / TS, s = i % TS;
    x_lds[c][s] = imgf[((size_t)b * 64 + c) * SS + s0 + s];
  }
  for (int i = tid; i < 96 * TS; i += 256) {
    int c = i / TS, s = i % TS;
    pf_lds[c][s] = pf[((size_t)b * 96 + c) * SS + s0 + s];
  }
  __syncthreads();

  for (int i = tid; i < 96 * TS; i += 256) {
    int oc = i / TS, s = i % TS;
    float a = b_img[oc];
#pragma unroll
    for (int c = 0; c < 64; ++c) a = fmaf(w_img[oc * 64 + c], x_lds[c][s], a);
    img_lds[oc][s] = fmaxf(a, 0.f);
  }
  __syncthreads();

  for (int i = tid; i < 24 * TS; i += 256) {
    int r = i / TS, s = i % TS;
    float a = b_fc2[r];
#pragma unroll
    for (int c = 0; c < 96; ++c) a = fmaf(w_fc2[r * 96 + c], img_lds[c][s], a);
    ri_lds[r][s] = tanhf(a);
  }
  __syncthreads();

  if (tid < TS) {
    float a = b_fc3[0];
#pragma unroll
    for (int r = 0; r < 24; ++r) a = fmaf(w_fc3[r], ri_lds[r][tid], a);
    att_lds[tid] = 1.f / (1.f + expf(-a));
  }
  __syncthreads();

  for (int i = tid; i < 96 * TS; i += 256) {
    int c = i / TS, s = i % TS;
    float v = img_lds[c][s];
    img_lds[c][s] = fmaf(v, att_lds[s], v);
  }
  __syncthreads();

  for (int i = tid; i < 96 * TS; i += 256) {
    int oc = i / TS, s = i % TS;
    float a = b_pc[oc];
#pragma unroll
    for (int c = 0; c < 96; ++c) a = fmaf(w_pc[oc * 96 + c], img_lds[c][s], a);
    imgn_lds[oc][s] = fmaxf(a, 0.f);
  }
  __syncthreads();

  for (int i = tid; i < 128 * TS; i += 256) {
    int oc = i / TS, s = i % TS;
    float a = b_fuse[oc];
#pragma unroll
    for (int c = 0; c < 96; ++c) a = fmaf(w_fuse[oc * 192 + c], pf_lds[c][s], a);
#pragma unroll
    for (int c = 0; c < 96; ++c) a = fmaf(w_fuse[oc * 192 + 96 + c], imgn_lds[c][s], a);
    out[((size_t)b * 128 + oc) * SS + s0 + s] = fmaxf(a, 0.f);
  }
}

// ---------------------------------------------------------------------------
extern "C" void kernel_launch(void* const* d_in, const int* in_sizes, int n_in,
                              void* d_out, int out_size, void* d_ws, size_t ws_size,
                              hipStream_t stream)
{
  const float* xyz    = (const float*)d_in[0];
  const float* feat   = (const float*)d_in[1];
  const float* imgf   = (const float*)d_in[2];
  const float* w0_0   = (const float*)d_in[3];
  const float* b0_0   = (const float*)d_in[4];
  const float* w0_1   = (const float*)d_in[5];
  const float* b0_1   = (const float*)d_in[6];
  const float* w0_2   = (const float*)d_in[7];
  const float* b0_2   = (const float*)d_in[8];
  const float* w1_0   = (const float*)d_in[9];
  const float* b1_0   = (const float*)d_in[10];
  const float* w1_1   = (const float*)d_in[11];
  const float* b1_1   = (const float*)d_in[12];
  const float* w1_2   = (const float*)d_in[13];
  const float* b1_2   = (const float*)d_in[14];
  const float* w_img  = (const float*)d_in[15];
  const float* b_img  = (const float*)d_in[16];
  const float* w_fc2  = (const float*)d_in[17];
  const float* b_fc2  = (const float*)d_in[18];
  const float* w_fc3  = (const float*)d_in[19];
  const float* b_fc3  = (const float*)d_in[20];
  const float* w_pc   = (const float*)d_in[21];
  const float* b_pc   = (const float*)d_in[22];
  const float* w_fuse = (const float*)d_in[23];
  const float* b_fuse = (const float*)d_in[24];
  float* out = (float*)d_out;

  float* sxA  = (float*)d_ws;                          // B*N f32
  float* syA  = sxA + (size_t)BB * NN;                 // B*N f32
  float* szA  = syA + (size_t)BB * NN;                 // B*N f32
  int*   siA  = (int*)(szA + (size_t)BB * NN);         // B*N i32
  float* nxyz = (float*)(siA + (size_t)BB * NN);       // B*S*3 f32
  int*   idx0 = (int*)(nxyz + (size_t)BB * SS * 3);    // B*S*16 i32
  int*   idx1 = idx0 + (size_t)BB * SS * 16;           // B*S*32 i32
  float* pf   = (float*)(idx1 + (size_t)BB * SS * 32); // B*96*S f32

  sort_kernel<<<BB, 1024, 0, stream>>>(xyz, sxA, syA, szA, siA);
  fps_kernel<<<BB, 1024, 0, stream>>>(xyz, sxA, syA, szA, siA, nxyz);
  ballq_kernel<16><<<BB * SS / 4, 256, 0, stream>>>(xyz, nxyz, idx0, 0.25f);
  ballq_kernel<32><<<BB * SS / 4, 256, 0, stream>>>(xyz, nxyz, idx1, 1.0f);
  group_mlp_kernel<16, 16, 16, 32><<<BB * SS / 16, 256, 0, stream>>>(
      xyz, feat, nxyz, idx0, w0_0, b0_0, w0_1, b0_1, w0_2, b0_2, pf, 0);
  group_mlp_kernel<32, 32, 32, 64><<<BB * SS / 8, 256, 0, stream>>>(
      xyz, feat, nxyz, idx1, w1_0, b1_0, w1_1, b1_1, w1_2, b1_2, pf, 32);
  img_fuse_kernel<<<BB * SS / 32, 256, 0, stream>>>(
      imgf, pf, w_img, b_img, w_fc2, b_fc2, w_fc3, b_fc3, w_pc, b_pc,
      w_fuse, b_fuse, out);
}